// Round 2
// 401.223 us; speedup vs baseline: 1.0982x; 1.0982x over previous
//
#include <hip/hip_runtime.h>
#include <math.h>

#define EPSF 1e-10f
#define P_NODES (1 << 20)   // H*W per tree
#define T_FRONT 65536       // frontier: nodes < T_FRONT solved exactly first
#define T_C1    262144      // chunk boundaries
#define T_C2    524288

// Native clang vector types — required by __builtin_nontemporal_*.
typedef float vf4 __attribute__((ext_vector_type(4)));
typedef float vf2 __attribute__((ext_vector_type(2)));

// Packed per-node record: contribution value + parent index (-1 = root).
struct __align__(8) NodePair {
    float v;
    int   par;
};

// ---------------------------------------------------------------------------
// XCD-pinned block decomposition. HW dispatches blockIdx.x round-robin over
// the 8 XCDs (blockIdx.x % 8 == XCD, learn_hip m09/m157). With nTrees == 4,
// tree t owns XCDs {2t, 2t+1}: its random-walk working set (pairs hop region
// + out prefix, <= 6 MB/tree) stays in 2 private 4 MiB L2s instead of being
// mixed with the other trees across all 8. Perf heuristic only — mapping is
// bijective, so correctness never depends on the actual XCD assignment.
// Requires gridDim.x % 8 == 0 (all grids here are).
// ---------------------------------------------------------------------------
__device__ __forceinline__ void tree_decomp(int b, int& tree, int& jj)
{
    tree = (b & 7) >> 1;                 // XCD pair -> tree
    jj   = ((b >> 3) << 1) | (b & 1);    // within-tree block index
}

// ---------------------------------------------------------------------------
// K1: contrib = (x[p]-x[par]) * sigmoid(feats(attrs).w + b), packed out.
// attrs tile staged through LDS with float4 (dwordx4) coalesced loads.
// attrs is stream-once -> nontemporal, keep L2 for x-gather + pairs writes.
// ---------------------------------------------------------------------------
__global__ __launch_bounds__(256) void score_kernel(
    const float* __restrict__ x,
    const float* __restrict__ weight,
    const float* __restrict__ bias,
    const float* __restrict__ attrs,
    const int*   __restrict__ parents,
    NodePair*    __restrict__ dst,
    int N)
{
    __shared__ float sA[256 * 15];

    const int t = threadIdx.x;
    int tree, jj;
    tree_decomp(blockIdx.x, tree, jj);
    const int blockBase = (tree << 20) + (jj << 8);
    const int idx = blockBase + t;

    // 256 rows x 15 floats = 960 float4 loads, fully coalesced, 16 B/lane.
    const vf4* ab4 = (const vf4*)(attrs + (size_t)blockBase * 15);
    vf4* sA4 = (vf4*)sA;
#pragma unroll
    for (int k = t; k < 960; k += 256)
        sA4[k] = __builtin_nontemporal_load(&ab4[k]);

    const int n    = tree % N;
    const float* w = weight + n * 17;
    const float  b = bias[n];

    __syncthreads();

    const float* a = &sA[t * 15];

    float acc = b;
    acc += a[0] * w[0];
    acc += a[1] * w[1];
    acc += a[2] * w[2];
    acc += a[3] * w[3];
    acc += a[4] * w[4];

    const float a5 = a[5];
    const float a6 = a[6];
    const float a7 = a[7];

    acc += __logf(fabsf(a6)    + EPSF) * w[5];
    acc += __logf(fabsf(a7)    + EPSF) * w[6];
    acc += __logf(fabsf(a[8])  + EPSF) * w[7];
    acc += __logf(fabsf(a[9])  + EPSF) * w[8];
    acc += __logf(fabsf(a[10]) + EPSF) * w[9];
    acc += __logf(fabsf(a[11]) + EPSF) * w[10];
    acc += __logf(fabsf(a[12]) + EPSF) * w[11];
    acc += __logf(fabsf(a[13]) + EPSF) * w[12];
    acc += __logf(fabsf(a[14]) + EPSF) * w[13];

    const float lshape = __fsqrt_rn(a7) / (__fsqrt_rn(a6) + EPSF);
    acc += lshape * w[14];
    acc += __cosf(a5) * w[15];
    acc += __sinf(a5) * w[16];

    const float score = 1.0f / (1.0f + __expf(-acc));

    const int   p   = idx & (P_NODES - 1);
    const int   par = parents[idx];
    const float xv  = x[idx];

    NodePair r;
    if (par == p) {                       // root (index 0 per generator)
        r.v   = xv * score;
        r.par = -1;
    } else {
        r.v   = (xv - x[(idx - p) + par]) * score;
        r.par = par;
    }
    dst[idx] = r;
}

// ---------------------------------------------------------------------------
// K2: frontier — exact root-to-node path sums for p < T_FRONT, written
// DIRECTLY into out (final values). Working set 512 KB/tree, L2-hot on the
// tree's pinned XCD pair. 1 node/thread for max TLP (latency-bound chasing).
// ---------------------------------------------------------------------------
__global__ __launch_bounds__(256) void frontier_kernel(
    const NodePair* __restrict__ pairs,
    float*          __restrict__ out)
{
    int tree, jj;
    tree_decomp(blockIdx.x, tree, jj);
    const int p    = (jj << 8) + threadIdx.x;     // < T_FRONT
    const int base = tree << 20;
    const NodePair* tp = pairs + base;

    NodePair r = tp[p];
    float s = r.v;
    int   c = r.par;
    while (c >= 0) {
        NodePair q = tp[c];
        s += q.v;
        c  = q.par;
    }
    out[base + p] = s;
}

// ---------------------------------------------------------------------------
// K3..K5: chunk propagation for p in [lo, hi): walk pairs while cur >= lo
// (indices ~halve per hop), then add the final out[cur] (cur < lo, written
// by an earlier kernel). Grid sized exactly per chunk.
// last=1 -> out stores are never re-read: nontemporal.
// ---------------------------------------------------------------------------
__global__ __launch_bounds__(256) void chunk_kernel(
    const NodePair* __restrict__ pairs,
    float*          __restrict__ out,
    int lo, int last)
{
    int tree, jj;
    tree_decomp(blockIdx.x, tree, jj);
    const int p0   = lo + ((((jj << 8) + threadIdx.x)) << 1);
    const int base = tree << 20;
    const NodePair* tp = pairs + base;

    float4 r = *(const float4*)(tp + p0);
    float s0 = r.x;  int c0 = __float_as_int(r.y);
    float s1 = r.z;  int c1 = __float_as_int(r.w);

    bool a0 = (c0 >= lo), a1 = (c1 >= lo);
    while (a0 || a1) {
        NodePair q0, q1;
        if (a0) q0 = tp[c0];
        if (a1) q1 = tp[c1];
        if (a0) { s0 += q0.v; c0 = q0.par; a0 = (c0 >= lo); }
        if (a1) { s1 += q1.v; c1 = q1.par; a1 = (c1 >= lo); }
    }
    // c < lo here; p >= lo >= 64K can never be the root, so c >= 0.
    s0 += out[base + c0];
    s1 += out[base + c1];

    vf2 o; o.x = s0; o.y = s1;
    if (last)
        __builtin_nontemporal_store(o, (vf2*)(out + base + p0));
    else
        *(vf2*)(out + base + p0) = o;
}

extern "C" void kernel_launch(void* const* d_in, const int* in_sizes, int n_in,
                              void* d_out, int out_size, void* d_ws, size_t ws_size,
                              hipStream_t stream)
{
    const float* x       = (const float*)d_in[0];
    const float* weight  = (const float*)d_in[1];
    const float* bias    = (const float*)d_in[2];
    const float* attrs   = (const float*)d_in[3];
    const int*   parents = (const int*)d_in[4];
    float*       out     = (float*)d_out;

    const int total  = in_sizes[0];           // B*N*P = 4194304
    const int N      = in_sizes[1] / 17;      // weight is (N,17,1)
    const int nTrees = total >> 20;           // 4

    NodePair* pairs = (NodePair*)d_ws;        // 32 MB

    const int block = 256;

    // K1: score + packed contrib/parent. 16384 blocks (mult. of 8, pinned).
    score_kernel<<<total / block, block, 0, stream>>>(x, weight, bias, attrs,
                                                      parents, pairs, N);

    // K2: [0, 64K) exact walks, final values straight into out. 1024 blocks.
    frontier_kernel<<<(T_FRONT / block) * nTrees, block, 0, stream>>>(pairs, out);

    // K3: [64K, 256K), barrier lo=64K. 1536 blocks.
    chunk_kernel<<<((T_C1 - T_FRONT) / (2 * block)) * nTrees, block, 0, stream>>>(
        pairs, out, T_FRONT, 0);

    // K4: [256K, 512K), barrier lo=256K. 2048 blocks.
    chunk_kernel<<<((T_C2 - T_C1) / (2 * block)) * nTrees, block, 0, stream>>>(
        pairs, out, T_C1, 0);

    // K5: [512K, 1M), barrier lo=512K. 4096 blocks, terminal stores NT.
    chunk_kernel<<<((P_NODES - T_C2) / (2 * block)) * nTrees, block, 0, stream>>>(
        pairs, out, T_C2, 1);
}